// Round 7
// baseline (257.491 us; speedup 1.0000x reference)
//
#include <hip/hip_runtime.h>

// B=8, L=1024, H=1024, NH=16, HD=64. fp32 I/O, bf16 MFMA internals.
// Pipeline: cvt3     : x,w_qkv,w_out fp32 -> bf16                  (~13 us)
//           gemm16<0>: qk = x@w_qkv^T cols<2048; V scatters to Vt  (51.5 GF)
//           attn     : no-max softmax flash attn, S^T trick        (34.4 GF)
//           gemm16<1>: out = O@w_out^T + b_out (fp32 out)          (17.2 GF)
// R7 (attn only): double-buffered K/V with async prefetch — tile t+1's
// global_load_lds issues right after the barrier publishing tile t, so the
// pre-barrier vmcnt(0) drain overlaps the whole compute phase (one barrier
// per iteration instead of two, exposed load latency ~0). Dual per-wave P
// buffers restored (R5 config). XCD-aware grid kept (FETCH at ideal 46 MB).

typedef short s16x8 __attribute__((ext_vector_type(8)));
typedef float f32x4 __attribute__((ext_vector_type(4)));
typedef unsigned int u32x2 __attribute__((ext_vector_type(2)));
typedef unsigned int u32x4 __attribute__((ext_vector_type(4)));

__device__ __forceinline__ unsigned short f2bf(float f) {   // RNE
    union { float f; unsigned u; } c; c.f = f;
    return (unsigned short)((c.u + 0x7FFFu + ((c.u >> 16) & 1u)) >> 16);
}
// pack 2 floats -> 2 bf16 (round-half-up) in 3 VALU ops via v_perm
__device__ __forceinline__ unsigned pack2bf(float a, float b) {
    union { float f; unsigned u; } ca, cb; ca.f = a; cb.f = b;
    return __builtin_amdgcn_perm(cb.u + 0x8000u, ca.u + 0x8000u, 0x07060302u);
}

#define GLOAD_LDS(g, l) __builtin_amdgcn_global_load_lds( \
    (const __attribute__((address_space(1))) void*)(g),   \
    (__attribute__((address_space(3))) void*)(l), 16, 0, 0)

// ---------------------------------------------------------------------------
// fp32 -> bf16 convert for the three input tensors.
// ---------------------------------------------------------------------------
__global__ __launch_bounds__(256) void cvt3(
    const float* __restrict__ s0, unsigned short* __restrict__ d0, int n0,
    const float* __restrict__ s1, unsigned short* __restrict__ d1, int n1,
    const float* __restrict__ s2, unsigned short* __restrict__ d2, int n2)
{
    long i = ((long)blockIdx.x * 256 + threadIdx.x) * 8;
    const float* s; unsigned short* d; long off;
    if (i < n0)                  { s = s0; d = d0; off = i; }
    else if (i < (long)n0 + n1)  { s = s1; d = d1; off = i - n0; }
    else                         { s = s2; d = d2; off = i - n0 - n1; }
    f32x4 a = *(const f32x4*)(s + off);
    f32x4 b = *(const f32x4*)(s + off + 4);
    u32x4 r;
    r[0] = pack2bf(a[0], a[1]); r[1] = pack2bf(a[2], a[3]);
    r[2] = pack2bf(b[0], b[1]); r[3] = pack2bf(b[2], b[3]);
    *(u32x4*)(d + off) = r;
}

// ---------------------------------------------------------------------------
// GEMM: C[M,N] = A[M,K]*B[N,K]^T, bf16 in, fp32 accum. 128x128 tile, BK=64,
// global_load_lds dwordx4. LDS [128][64] elems, XOR swizzle: logical 16B
// chunk q of row r at physical chunk q ^ (r&7) -> 2-way on banks (free).
// EPI=0: cols<2048 -> Cq bf16 (stride 2048); cols>=2048 (V) packed-scatter
//        to Cv = Vt[(b*16+h)*64+d][l] bf16.   EPI=1: Cf fp32 + bias.
// ---------------------------------------------------------------------------
template<int EPI>
__global__ __launch_bounds__(256) void gemm16(
    const unsigned short* __restrict__ A, const unsigned short* __restrict__ Bm,
    unsigned short* __restrict__ Cq, unsigned short* __restrict__ Cv,
    float* __restrict__ Cf, const float* __restrict__ bias,
    int N, int K)
{
    __shared__ unsigned short As[128 * 64];
    __shared__ unsigned short Bs[128 * 64];
    const int tid = threadIdx.x, lane = tid & 63, wave = tid >> 6;
    const int quad = lane >> 4, l16 = lane & 15;
    const int wm = (wave >> 1) * 64, wn = (wave & 1) * 64;
    const int m0 = blockIdx.y * 128, n0 = blockIdx.x * 128;

    const int prow = tid >> 3;
    const int qch  = (tid & 7) ^ (prow & 7);
    const unsigned short* gA[4];
    const unsigned short* gB[4];
    #pragma unroll
    for (int c = 0; c < 4; ++c) {
        gA[c] = A + (size_t)(m0 + c * 32 + prow) * K + qch * 8;
        gB[c] = Bm + (size_t)(n0 + c * 32 + prow) * K + qch * 8;
    }
    const int sw = l16 & 7;   // frag-read swizzle

    f32x4 acc[4][4] = {};
    for (int k0 = 0; k0 < K; k0 += 64) {
        __syncthreads();
        #pragma unroll
        for (int c = 0; c < 4; ++c) {
            GLOAD_LDS(gA[c], As + (c * 256 + tid) * 8);
            GLOAD_LDS(gB[c], Bs + (c * 256 + tid) * 8);
            gA[c] += 64; gB[c] += 64;
        }
        __syncthreads();
        #pragma unroll
        for (int s = 0; s < 2; ++s) {
            s16x8 af[4], bf[4];
            const int pc = ((s * 4 + quad) ^ sw) * 8;
            #pragma unroll
            for (int i = 0; i < 4; ++i)
                af[i] = *(const s16x8*)(As + (wm + i * 16 + l16) * 64 + pc);
            #pragma unroll
            for (int j = 0; j < 4; ++j)
                bf[j] = *(const s16x8*)(Bs + (wn + j * 16 + l16) * 64 + pc);
            #pragma unroll
            for (int i = 0; i < 4; ++i)
                #pragma unroll
                for (int j = 0; j < 4; ++j)
                    acc[i][j] = __builtin_amdgcn_mfma_f32_16x16x32_bf16(af[i], bf[j], acc[i][j], 0, 0, 0);
        }
    }

    // epilogue: C/D layout col=lane&15, row=quad*4+reg
    if (EPI == 1) {
        #pragma unroll
        for (int j = 0; j < 4; ++j) {
            int col = n0 + wn + j * 16 + l16;
            float bv = bias[col];
            #pragma unroll
            for (int i = 0; i < 4; ++i)
                #pragma unroll
                for (int r = 0; r < 4; ++r)
                    Cf[(size_t)(m0 + wm + i * 16 + quad * 4 + r) * N + col] = acc[i][j][r] + bv;
        }
    } else if (n0 < 2048) {
        #pragma unroll
        for (int j = 0; j < 4; ++j) {
            int col = n0 + wn + j * 16 + l16;
            #pragma unroll
            for (int i = 0; i < 4; ++i)
                #pragma unroll
                for (int r = 0; r < 4; ++r)
                    Cq[(size_t)(m0 + wm + i * 16 + quad * 4 + r) * 2048 + col] = f2bf(acc[i][j][r]);
        }
    } else {
        // V region: lane's r=0..3 are 4 consecutive l -> one 8B packed store
        #pragma unroll
        for (int j = 0; j < 4; ++j) {
            int dcol = n0 + wn + j * 16 + l16 - 2048;
            int hh = dcol >> 6, dd = dcol & 63;
            #pragma unroll
            for (int i = 0; i < 4; ++i) {
                int row = m0 + wm + i * 16 + quad * 4;
                int bb = row >> 10, l = row & 1023;
                u32x2 pw;
                pw[0] = pack2bf(acc[i][j][0], acc[i][j][1]);
                pw[1] = pack2bf(acc[i][j][2], acc[i][j][3]);
                *(u32x2*)(Cv + (size_t)((bb * 16 + hh) * 64 + dd) * 1024 + l) = pw;
            }
        }
    }
}

// ---------------------------------------------------------------------------
// Flash attention, no-max softmax, S^T trick, 128 q-rows per block (two
// 16-row halves per wave), double-buffered async K/V prefetch:
//   prologue: issue tile0 loads
//   loop t:   sync (publishes tile t; drain overlapped by prior compute);
//             issue tile t+1 -> other buffer; compute tile t
// One barrier/iter; exposed load latency ~0. Dual per-wave P buffers.
// Grid (128 bh, 8 qtile): id%8 = bh%8 -> head's K/V stays on one XCD L2.
// LDS 50 KB -> 3 blocks/CU.
// ---------------------------------------------------------------------------
__global__ __launch_bounds__(256) void attn(
    const unsigned short* __restrict__ qk, const unsigned short* __restrict__ Vt,
    unsigned short* __restrict__ O)
{
    __shared__ unsigned short Ks[2][64 * 64];     // [kv_local][d]  (swizzled)
    __shared__ unsigned short Vs[2][64 * 64];     // [d][kv_local]  (swizzled)
    __shared__ unsigned short Ps[4][2][16 * 72];  // per wave, per half

    const int bh = blockIdx.x, b = bh >> 4, hh = bh & 15;
    const int q0 = blockIdx.y * 128;
    const int tid = threadIdx.x, lane = tid & 63, wave = tid >> 6;
    const int quad = lane >> 4, l16 = lane & 15;

    // Q frags direct from global: B-operand, n=q, k=s*32+quad*8
    s16x8 qf[2][2];
    #pragma unroll
    for (int h = 0; h < 2; ++h) {
        const unsigned short* qrow =
            qk + (size_t)(b * 1024 + q0 + h * 64 + wave * 16 + l16) * 2048 + hh * 64;
        qf[h][0] = *(const s16x8*)(qrow + quad * 8);
        qf[h][1] = *(const s16x8*)(qrow + 32 + quad * 8);
    }

    // K/V staging: wave covers row-groups g0,g1 (8 rows x 8 chunks = 1KB);
    // physical (row = g*8 + (lane>>3), pc = lane&7); logical chunk = pc ^ (row&7).
    const int rl = lane >> 3;
    const int qc = (lane & 7) ^ rl;
    const int g0 = wave * 2, g1 = g0 + 1;
    const unsigned short* srcK0 = qk + (size_t)(b * 1024 + g0 * 8 + rl) * 2048 + 1024 + hh * 64 + qc * 8;
    const unsigned short* srcK1 = qk + (size_t)(b * 1024 + g1 * 8 + rl) * 2048 + 1024 + hh * 64 + qc * 8;
    const unsigned short* srcV0 = Vt + (size_t)(bh * 64 + g0 * 8 + rl) * 1024 + qc * 8;
    const unsigned short* srcV1 = Vt + (size_t)(bh * 64 + g1 * 8 + rl) * 1024 + qc * 8;
    const int oK0 = g0 * 512 + lane * 8, oK1 = g1 * 512 + lane * 8;

    const int sw = l16 & 7;   // frag-read swizzle

    f32x4 Oacc[2][4] = {};
    float lsum[2] = {0.0f, 0.0f};

    // prologue: issue tile 0 into buffer 0
    GLOAD_LDS(srcK0, &Ks[0][0] + oK0);
    GLOAD_LDS(srcK1, &Ks[0][0] + oK1);
    GLOAD_LDS(srcV0, &Vs[0][0] + oK0);
    GLOAD_LDS(srcV1, &Vs[0][0] + oK1);
    srcK0 += (size_t)64 * 2048; srcK1 += (size_t)64 * 2048;
    srcV0 += 64; srcV1 += 64;

    for (int t = 0; t < 16; ++t) {
        __syncthreads();   // publishes tile t (its loads overlapped prior compute)
        const int cur = t & 1, nxt = cur ^ 1;
        if (t < 15) {      // issue tile t+1 async into the other buffer
            GLOAD_LDS(srcK0, &Ks[nxt][0] + oK0);
            GLOAD_LDS(srcK1, &Ks[nxt][0] + oK1);
            GLOAD_LDS(srcV0, &Vs[nxt][0] + oK0);
            GLOAD_LDS(srcV1, &Vs[nxt][0] + oK1);
            srcK0 += (size_t)64 * 2048; srcK1 += (size_t)64 * 2048;
            srcV0 += 64; srcV1 += 64;
        }
        const unsigned short* Kc = &Ks[cur][0];
        const unsigned short* Vc = &Vs[cur][0];

        #pragma unroll
        for (int h = 0; h < 2; ++h) {
            unsigned short* Pw = &Ps[wave][h][0];
            // S^T = K Q^T : rows kv = j*16+quad*4+r, col q = l16
            f32x4 Sacc[4] = {};
            #pragma unroll
            for (int j = 0; j < 4; ++j) {
                #pragma unroll
                for (int s = 0; s < 2; ++s) {
                    s16x8 kf = *(const s16x8*)(Kc + (j * 16 + l16) * 64 + ((s * 4 + quad) ^ sw) * 8);
                    Sacc[j] = __builtin_amdgcn_mfma_f32_16x16x32_bf16(kf, qf[h][s], Sacc[j], 0, 0, 0);
                }
            }
            // p = exp(s/8); per-lane row-sum; pack + ds_write_b64 P[q=l16][kv]
            #pragma unroll
            for (int j = 0; j < 4; ++j) {
                float p0 = __expf(Sacc[j][0] * 0.125f);
                float p1 = __expf(Sacc[j][1] * 0.125f);
                float p2 = __expf(Sacc[j][2] * 0.125f);
                float p3 = __expf(Sacc[j][3] * 0.125f);
                lsum[h] += (p0 + p1) + (p2 + p3);
                u32x2 pw;
                pw[0] = pack2bf(p0, p1);
                pw[1] = pack2bf(p2, p3);
                *(u32x2*)(Pw + l16 * 72 + j * 16 + quad * 4) = pw;
            }
            asm volatile("s_waitcnt lgkmcnt(0)" ::: "memory");  // wave-local P ready
            // O += P V^T : A=P[m=q], B=Vs[n=d]
            #pragma unroll
            for (int s = 0; s < 2; ++s) {
                s16x8 pf = *(const s16x8*)(Pw + l16 * 72 + s * 32 + quad * 8);
                #pragma unroll
                for (int j = 0; j < 4; ++j) {
                    s16x8 vf = *(const s16x8*)(Vc + (j * 16 + l16) * 64 + ((s * 4 + quad) ^ sw) * 8);
                    Oacc[h][j] = __builtin_amdgcn_mfma_f32_16x16x32_bf16(pf, vf, Oacc[h][j], 0, 0, 0);
                }
            }
        }
    }

    // row-sum reduce + write
    #pragma unroll
    for (int h = 0; h < 2; ++h) {
        float ls = lsum[h];
        ls += __shfl_xor(ls, 16, 64);
        ls += __shfl_xor(ls, 32, 64);
        float rinv[4];
        #pragma unroll
        for (int r = 0; r < 4; ++r)
            rinv[r] = 1.0f / __shfl(ls, quad * 4 + r, 64);
        #pragma unroll
        for (int j = 0; j < 4; ++j)
            #pragma unroll
            for (int r = 0; r < 4; ++r) {
                int row = q0 + h * 64 + wave * 16 + quad * 4 + r;
                int col = hh * 64 + j * 16 + l16;
                O[(size_t)(b * 1024 + row) * 1024 + col] = f2bf(Oacc[h][j][r] * rinv[r]);
            }
    }
}

extern "C" void kernel_launch(void* const* d_in, const int* in_sizes, int n_in,
                              void* d_out, int out_size, void* d_ws, size_t ws_size,
                              hipStream_t stream) {
    const float* x     = (const float*)d_in[0];   // [8192,1024]
    const float* w_qkv = (const float*)d_in[1];   // [3072,1024]
    const float* w_out = (const float*)d_in[2];   // [1024,1024]
    const float* b_out = (const float*)d_in[3];   // [1024]
    float* out = (float*)d_out;                   // [8192,1024] fp32

    const int nx = 8192 * 1024, nwq = 3072 * 1024, nwo = 1024 * 1024;
    unsigned short* xb  = (unsigned short*)d_ws;          // 16.8 MB (dead after gemm1)
    unsigned short* wqb = xb + nx;                        //  6.3 MB
    unsigned short* wob = wqb + nwq;                      //  2.1 MB
    unsigned short* qkb = wob + nwo;                      // [8192,2048] Q|K, 33.6 MB
    unsigned short* Vt  = qkb + (size_t)8192 * 2048;      // [128*64,1024], 16.8 MB
    unsigned short* Ob  = xb;                             // alias: xb dead after gemm1

    dim3 blk(256);
    cvt3<<<6144, blk, 0, stream>>>(x, xb, nx, w_qkv, wqb, nwq, w_out, wob, nwo);
    gemm16<0><<<dim3(24, 64), blk, 0, stream>>>(xb, wqb, qkb, Vt, nullptr, nullptr, 3072, 1024);
    attn<<<dim3(128, 8), blk, 0, stream>>>(qkb, Vt, Ob);
    gemm16<1><<<dim3(8, 64), blk, 0, stream>>>(Ob, wob, nullptr, nullptr, out, b_out, 1024, 1024);
}

// Round 8
// 236.513 us; speedup vs baseline: 1.0887x; 1.0887x over previous
//
#include <hip/hip_runtime.h>

// B=8, L=1024, H=1024, NH=16, HD=64. fp32 I/O, bf16 MFMA internals.
// Pipeline: cvt3     : x,w_qkv,w_out fp32 -> bf16                  (~13 us)
//           gemm16<0>: qk = x@w_qkv^T cols<2048; V scatters to Vt  (51.5 GF)
//           attn     : no-max softmax flash attn, S^T trick        (34.4 GF)
//           gemm16<1>: out = O@w_out^T + b_out (fp32 out)          (17.2 GF)
// R8: attn reverted to the R5 structure (best measured: TLP-bound, 34.8 KB
// LDS, dual per-wave P, grid (8 qtile, 128 bh) — XCD grid & dbuf both lost).
// New: softmax scale 0.125*log2(e) pre-folded into Q at gemm1's epilogue
// (exact fp32 mul before the one bf16 rounding), so attn uses native
// v_exp_f32 (2^x) with no per-element multiply.

typedef short s16x8 __attribute__((ext_vector_type(8)));
typedef float f32x4 __attribute__((ext_vector_type(4)));
typedef unsigned int u32x2 __attribute__((ext_vector_type(2)));
typedef unsigned int u32x4 __attribute__((ext_vector_type(4)));

__device__ __forceinline__ unsigned short f2bf(float f) {   // RNE
    union { float f; unsigned u; } c; c.f = f;
    return (unsigned short)((c.u + 0x7FFFu + ((c.u >> 16) & 1u)) >> 16);
}
// pack 2 floats -> 2 bf16 (round-half-up) in 3 VALU ops via v_perm
__device__ __forceinline__ unsigned pack2bf(float a, float b) {
    union { float f; unsigned u; } ca, cb; ca.f = a; cb.f = b;
    return __builtin_amdgcn_perm(cb.u + 0x8000u, ca.u + 0x8000u, 0x07060302u);
}

#define GLOAD_LDS(g, l) __builtin_amdgcn_global_load_lds( \
    (const __attribute__((address_space(1))) void*)(g),   \
    (__attribute__((address_space(3))) void*)(l), 16, 0, 0)

// ---------------------------------------------------------------------------
// fp32 -> bf16 convert for the three input tensors.
// ---------------------------------------------------------------------------
__global__ __launch_bounds__(256) void cvt3(
    const float* __restrict__ s0, unsigned short* __restrict__ d0, int n0,
    const float* __restrict__ s1, unsigned short* __restrict__ d1, int n1,
    const float* __restrict__ s2, unsigned short* __restrict__ d2, int n2)
{
    long i = ((long)blockIdx.x * 256 + threadIdx.x) * 8;
    const float* s; unsigned short* d; long off;
    if (i < n0)                  { s = s0; d = d0; off = i; }
    else if (i < (long)n0 + n1)  { s = s1; d = d1; off = i - n0; }
    else                         { s = s2; d = d2; off = i - n0 - n1; }
    f32x4 a = *(const f32x4*)(s + off);
    f32x4 b = *(const f32x4*)(s + off + 4);
    u32x4 r;
    r[0] = pack2bf(a[0], a[1]); r[1] = pack2bf(a[2], a[3]);
    r[2] = pack2bf(b[0], b[1]); r[3] = pack2bf(b[2], b[3]);
    *(u32x4*)(d + off) = r;
}

// ---------------------------------------------------------------------------
// GEMM: C[M,N] = A[M,K]*B[N,K]^T, bf16 in, fp32 accum. 128x128 tile, BK=64,
// global_load_lds dwordx4. LDS [128][64] elems, XOR swizzle: logical 16B
// chunk q of row r at physical chunk q ^ (r&7) -> 2-way on banks (free).
// EPI=0: cols<1024 (Q) -> Cq bf16 scaled by 0.125*log2(e) (softmax prefold);
//        cols 1024..2047 (K) -> Cq bf16 unscaled; cols>=2048 (V) packed-
//        scatter to Cv = Vt[(b*16+h)*64+d][l] bf16.
// EPI=1: Cf fp32 + bias.
// ---------------------------------------------------------------------------
template<int EPI>
__global__ __launch_bounds__(256) void gemm16(
    const unsigned short* __restrict__ A, const unsigned short* __restrict__ Bm,
    unsigned short* __restrict__ Cq, unsigned short* __restrict__ Cv,
    float* __restrict__ Cf, const float* __restrict__ bias,
    int N, int K)
{
    __shared__ unsigned short As[128 * 64];
    __shared__ unsigned short Bs[128 * 64];
    const int tid = threadIdx.x, lane = tid & 63, wave = tid >> 6;
    const int quad = lane >> 4, l16 = lane & 15;
    const int wm = (wave >> 1) * 64, wn = (wave & 1) * 64;
    const int m0 = blockIdx.y * 128, n0 = blockIdx.x * 128;

    const int prow = tid >> 3;
    const int qch  = (tid & 7) ^ (prow & 7);
    const unsigned short* gA[4];
    const unsigned short* gB[4];
    #pragma unroll
    for (int c = 0; c < 4; ++c) {
        gA[c] = A + (size_t)(m0 + c * 32 + prow) * K + qch * 8;
        gB[c] = Bm + (size_t)(n0 + c * 32 + prow) * K + qch * 8;
    }
    const int sw = l16 & 7;   // frag-read swizzle

    f32x4 acc[4][4] = {};
    for (int k0 = 0; k0 < K; k0 += 64) {
        __syncthreads();
        #pragma unroll
        for (int c = 0; c < 4; ++c) {
            GLOAD_LDS(gA[c], As + (c * 256 + tid) * 8);
            GLOAD_LDS(gB[c], Bs + (c * 256 + tid) * 8);
            gA[c] += 64; gB[c] += 64;
        }
        __syncthreads();
        #pragma unroll
        for (int s = 0; s < 2; ++s) {
            s16x8 af[4], bf[4];
            const int pc = ((s * 4 + quad) ^ sw) * 8;
            #pragma unroll
            for (int i = 0; i < 4; ++i)
                af[i] = *(const s16x8*)(As + (wm + i * 16 + l16) * 64 + pc);
            #pragma unroll
            for (int j = 0; j < 4; ++j)
                bf[j] = *(const s16x8*)(Bs + (wn + j * 16 + l16) * 64 + pc);
            #pragma unroll
            for (int i = 0; i < 4; ++i)
                #pragma unroll
                for (int j = 0; j < 4; ++j)
                    acc[i][j] = __builtin_amdgcn_mfma_f32_16x16x32_bf16(af[i], bf[j], acc[i][j], 0, 0, 0);
        }
    }

    // epilogue: C/D layout col=lane&15, row=quad*4+reg
    if (EPI == 1) {
        #pragma unroll
        for (int j = 0; j < 4; ++j) {
            int col = n0 + wn + j * 16 + l16;
            float bv = bias[col];
            #pragma unroll
            for (int i = 0; i < 4; ++i)
                #pragma unroll
                for (int r = 0; r < 4; ++r)
                    Cf[(size_t)(m0 + wm + i * 16 + quad * 4 + r) * N + col] = acc[i][j][r] + bv;
        }
    } else if (n0 < 2048) {
        // Q region: prefold softmax scale (1/8) and log2(e) for native exp2
        const float qs = (n0 < 1024) ? 0.18033688f : 1.0f;   // 0.125*log2(e)
        #pragma unroll
        for (int j = 0; j < 4; ++j) {
            int col = n0 + wn + j * 16 + l16;
            #pragma unroll
            for (int i = 0; i < 4; ++i)
                #pragma unroll
                for (int r = 0; r < 4; ++r)
                    Cq[(size_t)(m0 + wm + i * 16 + quad * 4 + r) * 2048 + col] = f2bf(acc[i][j][r] * qs);
        }
    } else {
        // V region: lane's r=0..3 are 4 consecutive l -> one 8B packed store
        #pragma unroll
        for (int j = 0; j < 4; ++j) {
            int dcol = n0 + wn + j * 16 + l16 - 2048;
            int hh = dcol >> 6, dd = dcol & 63;
            #pragma unroll
            for (int i = 0; i < 4; ++i) {
                int row = m0 + wm + i * 16 + quad * 4;
                int bb = row >> 10, l = row & 1023;
                u32x2 pw;
                pw[0] = pack2bf(acc[i][j][0], acc[i][j][1]);
                pw[1] = pack2bf(acc[i][j][2], acc[i][j][3]);
                *(u32x2*)(Cv + (size_t)((bb * 16 + hh) * 64 + dd) * 1024 + l) = pw;
            }
        }
    }
}

// ---------------------------------------------------------------------------
// Flash attention, no-max softmax (Q pre-scaled by 0.125*log2e -> bare exp2),
// S^T trick, async-staged K/V, 128 q-rows per block (two 16-row halves per
// wave share each staged K/V tile). R5 structure: 2-barrier loop, dual
// per-wave P buffers, grid (8 qtile, 128 bh). LDS 34.8 KB -> 4 blocks/CU.
// ---------------------------------------------------------------------------
__global__ __launch_bounds__(256) void attn(
    const unsigned short* __restrict__ qk, const unsigned short* __restrict__ Vt,
    unsigned short* __restrict__ O)
{
    __shared__ unsigned short Ks[64 * 64];        // [kv_local][d]  (swizzled)
    __shared__ unsigned short Vs[64 * 64];        // [d][kv_local]  (swizzled)
    __shared__ unsigned short Ps[4][2][16 * 72];  // per wave, per half

    const int bh = blockIdx.y, b = bh >> 4, hh = bh & 15;
    const int q0 = blockIdx.x * 128;
    const int tid = threadIdx.x, lane = tid & 63, wave = tid >> 6;
    const int quad = lane >> 4, l16 = lane & 15;

    // Q frags direct from global: B-operand, n=q, k=s*32+quad*8
    s16x8 qf[2][2];
    #pragma unroll
    for (int h = 0; h < 2; ++h) {
        const unsigned short* qrow =
            qk + (size_t)(b * 1024 + q0 + h * 64 + wave * 16 + l16) * 2048 + hh * 64;
        qf[h][0] = *(const s16x8*)(qrow + quad * 8);
        qf[h][1] = *(const s16x8*)(qrow + 32 + quad * 8);
    }

    // K/V staging: wave covers row-groups g0,g1 (8 rows x 8 chunks = 1KB);
    // physical (row = g*8 + (lane>>3), pc = lane&7); logical chunk = pc ^ (row&7).
    const int rl = lane >> 3;
    const int qc = (lane & 7) ^ rl;
    const int g0 = wave * 2, g1 = g0 + 1;
    const unsigned short* srcK0 = qk + (size_t)(b * 1024 + g0 * 8 + rl) * 2048 + 1024 + hh * 64 + qc * 8;
    const unsigned short* srcK1 = qk + (size_t)(b * 1024 + g1 * 8 + rl) * 2048 + 1024 + hh * 64 + qc * 8;
    const unsigned short* srcV0 = Vt + (size_t)(bh * 64 + g0 * 8 + rl) * 1024 + qc * 8;
    const unsigned short* srcV1 = Vt + (size_t)(bh * 64 + g1 * 8 + rl) * 1024 + qc * 8;
    unsigned short* dK0 = Ks + g0 * 512 + lane * 8;
    unsigned short* dK1 = Ks + g1 * 512 + lane * 8;
    unsigned short* dV0 = Vs + g0 * 512 + lane * 8;
    unsigned short* dV1 = Vs + g1 * 512 + lane * 8;

    const int sw = l16 & 7;   // frag-read swizzle

    f32x4 Oacc[2][4] = {};
    float lsum[2] = {0.0f, 0.0f};

    for (int kv = 0; kv < 1024; kv += 64) {
        __syncthreads();
        GLOAD_LDS(srcK0, dK0);
        GLOAD_LDS(srcK1, dK1);
        GLOAD_LDS(srcV0, dV0);
        GLOAD_LDS(srcV1, dV1);
        srcK0 += (size_t)64 * 2048; srcK1 += (size_t)64 * 2048;
        srcV0 += 64; srcV1 += 64;
        __syncthreads();   // vmcnt(0) drain -> K,V in LDS

        #pragma unroll
        for (int h = 0; h < 2; ++h) {
            unsigned short* Pw = &Ps[wave][h][0];
            // S^T = K Q^T : rows kv = j*16+quad*4+r, col q = l16
            f32x4 Sacc[4] = {};
            #pragma unroll
            for (int j = 0; j < 4; ++j) {
                #pragma unroll
                for (int s = 0; s < 2; ++s) {
                    s16x8 kf = *(const s16x8*)(Ks + (j * 16 + l16) * 64 + ((s * 4 + quad) ^ sw) * 8);
                    Sacc[j] = __builtin_amdgcn_mfma_f32_16x16x32_bf16(kf, qf[h][s], Sacc[j], 0, 0, 0);
                }
            }
            // p = 2^s (scale prefolded into Q); per-lane row-sum; b64 P store
            #pragma unroll
            for (int j = 0; j < 4; ++j) {
                float p0 = __builtin_amdgcn_exp2f(Sacc[j][0]);
                float p1 = __builtin_amdgcn_exp2f(Sacc[j][1]);
                float p2 = __builtin_amdgcn_exp2f(Sacc[j][2]);
                float p3 = __builtin_amdgcn_exp2f(Sacc[j][3]);
                lsum[h] += (p0 + p1) + (p2 + p3);
                u32x2 pw;
                pw[0] = pack2bf(p0, p1);
                pw[1] = pack2bf(p2, p3);
                *(u32x2*)(Pw + l16 * 72 + j * 16 + quad * 4) = pw;
            }
            asm volatile("s_waitcnt lgkmcnt(0)" ::: "memory");  // wave-local P ready
            // O += P V^T : A=P[m=q], B=Vs[n=d]
            #pragma unroll
            for (int s = 0; s < 2; ++s) {
                s16x8 pf = *(const s16x8*)(Pw + l16 * 72 + s * 32 + quad * 8);
                #pragma unroll
                for (int j = 0; j < 4; ++j) {
                    s16x8 vf = *(const s16x8*)(Vs + (j * 16 + l16) * 64 + ((s * 4 + quad) ^ sw) * 8);
                    Oacc[h][j] = __builtin_amdgcn_mfma_f32_16x16x32_bf16(pf, vf, Oacc[h][j], 0, 0, 0);
                }
            }
        }
    }

    // row-sum reduce + write
    #pragma unroll
    for (int h = 0; h < 2; ++h) {
        float ls = lsum[h];
        ls += __shfl_xor(ls, 16, 64);
        ls += __shfl_xor(ls, 32, 64);
        float rinv[4];
        #pragma unroll
        for (int r = 0; r < 4; ++r)
            rinv[r] = 1.0f / __shfl(ls, quad * 4 + r, 64);
        #pragma unroll
        for (int j = 0; j < 4; ++j)
            #pragma unroll
            for (int r = 0; r < 4; ++r) {
                int row = q0 + h * 64 + wave * 16 + quad * 4 + r;
                int col = hh * 64 + j * 16 + l16;
                O[(size_t)(b * 1024 + row) * 1024 + col] = f2bf(Oacc[h][j][r] * rinv[r]);
            }
    }
}

extern "C" void kernel_launch(void* const* d_in, const int* in_sizes, int n_in,
                              void* d_out, int out_size, void* d_ws, size_t ws_size,
                              hipStream_t stream) {
    const float* x     = (const float*)d_in[0];   // [8192,1024]
    const float* w_qkv = (const float*)d_in[1];   // [3072,1024]
    const float* w_out = (const float*)d_in[2];   // [1024,1024]
    const float* b_out = (const float*)d_in[3];   // [1024]
    float* out = (float*)d_out;                   // [8192,1024] fp32

    const int nx = 8192 * 1024, nwq = 3072 * 1024, nwo = 1024 * 1024;
    unsigned short* xb  = (unsigned short*)d_ws;          // 16.8 MB (dead after gemm1)
    unsigned short* wqb = xb + nx;                        //  6.3 MB
    unsigned short* wob = wqb + nwq;                      //  2.1 MB
    unsigned short* qkb = wob + nwo;                      // [8192,2048] Q|K, 33.6 MB
    unsigned short* Vt  = qkb + (size_t)8192 * 2048;      // [128*64,1024], 16.8 MB
    unsigned short* Ob  = xb;                             // alias: xb dead after gemm1

    dim3 blk(256);
    cvt3<<<6144, blk, 0, stream>>>(x, xb, nx, w_qkv, wqb, nwq, w_out, wob, nwo);
    gemm16<0><<<dim3(24, 64), blk, 0, stream>>>(xb, wqb, qkb, Vt, nullptr, nullptr, 3072, 1024);
    attn<<<dim3(8, 128), blk, 0, stream>>>(qkb, Vt, Ob);
    gemm16<1><<<dim3(8, 64), blk, 0, stream>>>(Ob, wob, nullptr, nullptr, out, b_out, 1024, 1024);
}

// Round 9
// 235.997 us; speedup vs baseline: 1.0911x; 1.0022x over previous
//
#include <hip/hip_runtime.h>

// B=8, L=1024, H=1024, NH=16, HD=64. fp32 I/O, bf16 MFMA internals.
// Pipeline: cvt3     : x,w_qkv,w_out fp32 -> bf16                  (~13 us)
//           gemm16<0>: qk = x@w_qkv^T cols<2048; V scatters to Vt  (51.5 GF)
//           attn     : no-max softmax flash attn, S^T trick        (34.4 GF)
//           gemm16<1>: out = O@w_out^T + b_out (fp32 out)          (17.2 GF)
// R9 (attn): P never touches LDS. K-staging permutes kv rows into LDS
// (row 16t+4u+r <-> kv 32(t>>1)+8u+4(t&1)+r) so the S^T C-layout registers,
// packed to bf16 pairs, ARE the PV 16x16x32 A-fragment for kv-block s
// (tiles 2s,2s+1 give k=quad*8+{0..7}). Row-sums are permutation-invariant.
// Removes 16 ds_writes + 4 ds_reads + 2 waits per tile and 18.4 KB LDS.

typedef short s16x8 __attribute__((ext_vector_type(8)));
typedef float f32x4 __attribute__((ext_vector_type(4)));
typedef unsigned int u32x2 __attribute__((ext_vector_type(2)));
typedef unsigned int u32x4 __attribute__((ext_vector_type(4)));

__device__ __forceinline__ unsigned short f2bf(float f) {   // RNE
    union { float f; unsigned u; } c; c.f = f;
    return (unsigned short)((c.u + 0x7FFFu + ((c.u >> 16) & 1u)) >> 16);
}
// pack 2 floats -> 2 bf16 (round-half-up) in 3 VALU ops via v_perm
__device__ __forceinline__ unsigned pack2bf(float a, float b) {
    union { float f; unsigned u; } ca, cb; ca.f = a; cb.f = b;
    return __builtin_amdgcn_perm(cb.u + 0x8000u, ca.u + 0x8000u, 0x07060302u);
}

#define GLOAD_LDS(g, l) __builtin_amdgcn_global_load_lds( \
    (const __attribute__((address_space(1))) void*)(g),   \
    (__attribute__((address_space(3))) void*)(l), 16, 0, 0)

// ---------------------------------------------------------------------------
// fp32 -> bf16 convert for the three input tensors.
// ---------------------------------------------------------------------------
__global__ __launch_bounds__(256) void cvt3(
    const float* __restrict__ s0, unsigned short* __restrict__ d0, int n0,
    const float* __restrict__ s1, unsigned short* __restrict__ d1, int n1,
    const float* __restrict__ s2, unsigned short* __restrict__ d2, int n2)
{
    long i = ((long)blockIdx.x * 256 + threadIdx.x) * 8;
    const float* s; unsigned short* d; long off;
    if (i < n0)                  { s = s0; d = d0; off = i; }
    else if (i < (long)n0 + n1)  { s = s1; d = d1; off = i - n0; }
    else                         { s = s2; d = d2; off = i - n0 - n1; }
    f32x4 a = *(const f32x4*)(s + off);
    f32x4 b = *(const f32x4*)(s + off + 4);
    u32x4 r;
    r[0] = pack2bf(a[0], a[1]); r[1] = pack2bf(a[2], a[3]);
    r[2] = pack2bf(b[0], b[1]); r[3] = pack2bf(b[2], b[3]);
    *(u32x4*)(d + off) = r;
}

// ---------------------------------------------------------------------------
// GEMM: C[M,N] = A[M,K]*B[N,K]^T, bf16 in, fp32 accum. 128x128 tile, BK=64,
// global_load_lds dwordx4. LDS [128][64] elems, XOR swizzle: logical 16B
// chunk q of row r at physical chunk q ^ (r&7) -> 2-way on banks (free).
// EPI=0: cols<1024 (Q) -> Cq bf16 scaled by 0.125*log2(e) (softmax prefold);
//        cols 1024..2047 (K) -> Cq bf16 unscaled; cols>=2048 (V) packed-
//        scatter to Cv = Vt[(b*16+h)*64+d][l] bf16.
// EPI=1: Cf fp32 + bias.
// ---------------------------------------------------------------------------
template<int EPI>
__global__ __launch_bounds__(256) void gemm16(
    const unsigned short* __restrict__ A, const unsigned short* __restrict__ Bm,
    unsigned short* __restrict__ Cq, unsigned short* __restrict__ Cv,
    float* __restrict__ Cf, const float* __restrict__ bias,
    int N, int K)
{
    __shared__ unsigned short As[128 * 64];
    __shared__ unsigned short Bs[128 * 64];
    const int tid = threadIdx.x, lane = tid & 63, wave = tid >> 6;
    const int quad = lane >> 4, l16 = lane & 15;
    const int wm = (wave >> 1) * 64, wn = (wave & 1) * 64;
    const int m0 = blockIdx.y * 128, n0 = blockIdx.x * 128;

    const int prow = tid >> 3;
    const int qch  = (tid & 7) ^ (prow & 7);
    const unsigned short* gA[4];
    const unsigned short* gB[4];
    #pragma unroll
    for (int c = 0; c < 4; ++c) {
        gA[c] = A + (size_t)(m0 + c * 32 + prow) * K + qch * 8;
        gB[c] = Bm + (size_t)(n0 + c * 32 + prow) * K + qch * 8;
    }
    const int sw = l16 & 7;   // frag-read swizzle

    f32x4 acc[4][4] = {};
    for (int k0 = 0; k0 < K; k0 += 64) {
        __syncthreads();
        #pragma unroll
        for (int c = 0; c < 4; ++c) {
            GLOAD_LDS(gA[c], As + (c * 256 + tid) * 8);
            GLOAD_LDS(gB[c], Bs + (c * 256 + tid) * 8);
            gA[c] += 64; gB[c] += 64;
        }
        __syncthreads();
        #pragma unroll
        for (int s = 0; s < 2; ++s) {
            s16x8 af[4], bf[4];
            const int pc = ((s * 4 + quad) ^ sw) * 8;
            #pragma unroll
            for (int i = 0; i < 4; ++i)
                af[i] = *(const s16x8*)(As + (wm + i * 16 + l16) * 64 + pc);
            #pragma unroll
            for (int j = 0; j < 4; ++j)
                bf[j] = *(const s16x8*)(Bs + (wn + j * 16 + l16) * 64 + pc);
            #pragma unroll
            for (int i = 0; i < 4; ++i)
                #pragma unroll
                for (int j = 0; j < 4; ++j)
                    acc[i][j] = __builtin_amdgcn_mfma_f32_16x16x32_bf16(af[i], bf[j], acc[i][j], 0, 0, 0);
        }
    }

    // epilogue: C/D layout col=lane&15, row=quad*4+reg
    if (EPI == 1) {
        #pragma unroll
        for (int j = 0; j < 4; ++j) {
            int col = n0 + wn + j * 16 + l16;
            float bv = bias[col];
            #pragma unroll
            for (int i = 0; i < 4; ++i)
                #pragma unroll
                for (int r = 0; r < 4; ++r)
                    Cf[(size_t)(m0 + wm + i * 16 + quad * 4 + r) * N + col] = acc[i][j][r] + bv;
        }
    } else if (n0 < 2048) {
        // Q region: prefold softmax scale (1/8) and log2(e) for native exp2
        const float qs = (n0 < 1024) ? 0.18033688f : 1.0f;   // 0.125*log2(e)
        #pragma unroll
        for (int j = 0; j < 4; ++j) {
            int col = n0 + wn + j * 16 + l16;
            #pragma unroll
            for (int i = 0; i < 4; ++i)
                #pragma unroll
                for (int r = 0; r < 4; ++r)
                    Cq[(size_t)(m0 + wm + i * 16 + quad * 4 + r) * 2048 + col] = f2bf(acc[i][j][r] * qs);
        }
    } else {
        // V region: lane's r=0..3 are 4 consecutive l -> one 8B packed store
        #pragma unroll
        for (int j = 0; j < 4; ++j) {
            int dcol = n0 + wn + j * 16 + l16 - 2048;
            int hh = dcol >> 6, dd = dcol & 63;
            #pragma unroll
            for (int i = 0; i < 4; ++i) {
                int row = m0 + wm + i * 16 + quad * 4;
                int bb = row >> 10, l = row & 1023;
                u32x2 pw;
                pw[0] = pack2bf(acc[i][j][0], acc[i][j][1]);
                pw[1] = pack2bf(acc[i][j][2], acc[i][j][3]);
                *(u32x2*)(Cv + (size_t)((bb * 16 + hh) * 64 + dd) * 1024 + l) = pw;
            }
        }
    }
}

// ---------------------------------------------------------------------------
// Flash attention, no-max softmax (Q pre-scaled by 0.125*log2e -> bare exp2),
// S^T trick with kv-permuted K staging so P's packed C-layout registers are
// directly the PV A-fragments (no P LDS round-trip at all).
// K staging permutation: LDS row rho = 16t+4u+r holds kv = 32(t>>1)+8u+4(t&1)+r.
// Then lane (quad,l16) of S^T tile t holds kv = 32(t>>1)+8*quad+4(t&1)+r, so
// tiles {2s,2s+1} packed = A-frag k=quad*8+jj for kv-block s. V natural.
// 128 q-rows/block (two halves/wave), grid (8 qtile, 128 bh), LDS 16.4 KB.
// ---------------------------------------------------------------------------
__global__ __launch_bounds__(256) void attn(
    const unsigned short* __restrict__ qk, const unsigned short* __restrict__ Vt,
    unsigned short* __restrict__ O)
{
    __shared__ unsigned short Ks[64 * 64];   // [rho][d] kv-permuted, swizzled
    __shared__ unsigned short Vs[64 * 64];   // [d][kv]  natural, swizzled

    const int bh = blockIdx.y, b = bh >> 4, hh = bh & 15;
    const int q0 = blockIdx.x * 128;
    const int tid = threadIdx.x, lane = tid & 63, wave = tid >> 6;
    const int quad = lane >> 4, l16 = lane & 15;

    // Q frags direct from global: B-operand, n=q, k=s*32+quad*8
    s16x8 qf[2][2];
    #pragma unroll
    for (int h = 0; h < 2; ++h) {
        const unsigned short* qrow =
            qk + (size_t)(b * 1024 + q0 + h * 64 + wave * 16 + l16) * 2048 + hh * 64;
        qf[h][0] = *(const s16x8*)(qrow + quad * 8);
        qf[h][1] = *(const s16x8*)(qrow + 32 + quad * 8);
    }

    // Staging: wave covers LDS rows rho0 = wave*16+rl and rho1 = rho0+8
    // (rl = lane>>3); chunk swizzle qc = (lane&7) ^ (rho&7), rho&7 == rl.
    // K source rows are the PERMUTED kv for each rho (t = wave for both).
    const int rl = lane >> 3;
    const int qc = (lane & 7) ^ rl;
    const int u0 = rl >> 2, r0 = rl & 3;
    const int kvbase = 32 * (wave >> 1) + 4 * (wave & 1) + r0;
    const int kv0 = kvbase + 8 * u0;          // for LDS row wave*16 + rl
    const int kv1 = kvbase + 8 * (2 + u0);    // for LDS row wave*16 + 8 + rl
    const unsigned short* srcK0 = qk + (size_t)(b * 1024 + kv0) * 2048 + 1024 + hh * 64 + qc * 8;
    const unsigned short* srcK1 = qk + (size_t)(b * 1024 + kv1) * 2048 + 1024 + hh * 64 + qc * 8;
    const unsigned short* srcV0 = Vt + (size_t)(bh * 64 + wave * 16 + rl) * 1024 + qc * 8;
    const unsigned short* srcV1 = Vt + (size_t)(bh * 64 + wave * 16 + 8 + rl) * 1024 + qc * 8;
    unsigned short* dK0 = Ks + (wave * 16 + rl) * 64 + (lane & 7) * 8;
    unsigned short* dK1 = Ks + (wave * 16 + 8 + rl) * 64 + (lane & 7) * 8;
    unsigned short* dV0 = Vs + (wave * 16 + rl) * 64 + (lane & 7) * 8;
    unsigned short* dV1 = Vs + (wave * 16 + 8 + rl) * 64 + (lane & 7) * 8;

    const int sw = l16 & 7;   // frag-read swizzle

    f32x4 Oacc[2][4] = {};
    float lsum[2] = {0.0f, 0.0f};

    for (int kv = 0; kv < 1024; kv += 64) {
        __syncthreads();
        GLOAD_LDS(srcK0, dK0);
        GLOAD_LDS(srcK1, dK1);
        GLOAD_LDS(srcV0, dV0);
        GLOAD_LDS(srcV1, dV1);
        srcK0 += (size_t)64 * 2048; srcK1 += (size_t)64 * 2048;
        srcV0 += 64; srcV1 += 64;
        __syncthreads();   // vmcnt(0) drain -> K,V in LDS

        #pragma unroll
        for (int h = 0; h < 2; ++h) {
            // S^T = K Q^T : tile t rows = permuted kv, col q = l16
            f32x4 Sacc[4] = {};
            #pragma unroll
            for (int t = 0; t < 4; ++t) {
                #pragma unroll
                for (int s = 0; s < 2; ++s) {
                    s16x8 kf = *(const s16x8*)(Ks + (t * 16 + l16) * 64 + ((s * 4 + quad) ^ sw) * 8);
                    Sacc[t] = __builtin_amdgcn_mfma_f32_16x16x32_bf16(kf, qf[h][s], Sacc[t], 0, 0, 0);
                }
            }
            // p = 2^s; per-lane row-sum; pack pairs (these ARE the PV A-frags)
            unsigned upw[4][2];
            #pragma unroll
            for (int t = 0; t < 4; ++t) {
                float p0 = __builtin_amdgcn_exp2f(Sacc[t][0]);
                float p1 = __builtin_amdgcn_exp2f(Sacc[t][1]);
                float p2 = __builtin_amdgcn_exp2f(Sacc[t][2]);
                float p3 = __builtin_amdgcn_exp2f(Sacc[t][3]);
                lsum[h] += (p0 + p1) + (p2 + p3);
                upw[t][0] = pack2bf(p0, p1);
                upw[t][1] = pack2bf(p2, p3);
            }
            // O += P V^T : A = packed P (register), B = Vs[n=d] (natural)
            #pragma unroll
            for (int s = 0; s < 2; ++s) {
                u32x4 aw;
                aw[0] = upw[2 * s][0];     aw[1] = upw[2 * s][1];
                aw[2] = upw[2 * s + 1][0]; aw[3] = upw[2 * s + 1][1];
                s16x8 pf;
                __builtin_memcpy(&pf, &aw, 16);
                #pragma unroll
                for (int jd = 0; jd < 4; ++jd) {
                    s16x8 vf = *(const s16x8*)(Vs + (jd * 16 + l16) * 64 + ((s * 4 + quad) ^ sw) * 8);
                    Oacc[h][jd] = __builtin_amdgcn_mfma_f32_16x16x32_bf16(pf, vf, Oacc[h][jd], 0, 0, 0);
                }
            }
        }
    }

    // row-sum reduce + write (sum over quads is permutation-invariant)
    #pragma unroll
    for (int h = 0; h < 2; ++h) {
        float ls = lsum[h];
        ls += __shfl_xor(ls, 16, 64);
        ls += __shfl_xor(ls, 32, 64);
        float rinv[4];
        #pragma unroll
        for (int r = 0; r < 4; ++r)
            rinv[r] = 1.0f / __shfl(ls, quad * 4 + r, 64);
        #pragma unroll
        for (int j = 0; j < 4; ++j)
            #pragma unroll
            for (int r = 0; r < 4; ++r) {
                int row = q0 + h * 64 + wave * 16 + quad * 4 + r;
                int col = hh * 64 + j * 16 + l16;
                O[(size_t)(b * 1024 + row) * 1024 + col] = f2bf(Oacc[h][j][r] * rinv[r]);
            }
    }
}

extern "C" void kernel_launch(void* const* d_in, const int* in_sizes, int n_in,
                              void* d_out, int out_size, void* d_ws, size_t ws_size,
                              hipStream_t stream) {
    const float* x     = (const float*)d_in[0];   // [8192,1024]
    const float* w_qkv = (const float*)d_in[1];   // [3072,1024]
    const float* w_out = (const float*)d_in[2];   // [1024,1024]
    const float* b_out = (const float*)d_in[3];   // [1024]
    float* out = (float*)d_out;                   // [8192,1024] fp32

    const int nx = 8192 * 1024, nwq = 3072 * 1024, nwo = 1024 * 1024;
    unsigned short* xb  = (unsigned short*)d_ws;          // 16.8 MB (dead after gemm1)
    unsigned short* wqb = xb + nx;                        //  6.3 MB
    unsigned short* wob = wqb + nwq;                      //  2.1 MB
    unsigned short* qkb = wob + nwo;                      // [8192,2048] Q|K, 33.6 MB
    unsigned short* Vt  = qkb + (size_t)8192 * 2048;      // [128*64,1024], 16.8 MB
    unsigned short* Ob  = xb;                             // alias: xb dead after gemm1

    dim3 blk(256);
    cvt3<<<6144, blk, 0, stream>>>(x, xb, nx, w_qkv, wqb, nwq, w_out, wob, nwo);
    gemm16<0><<<dim3(24, 64), blk, 0, stream>>>(xb, wqb, qkb, Vt, nullptr, nullptr, 3072, 1024);
    attn<<<dim3(8, 128), blk, 0, stream>>>(qkb, Vt, Ob);
    gemm16<1><<<dim3(8, 64), blk, 0, stream>>>(Ob, wob, nullptr, nullptr, out, b_out, 1024, 1024);
}

// Round 10
// 234.184 us; speedup vs baseline: 1.0995x; 1.0077x over previous
//
#include <hip/hip_runtime.h>

// B=8, L=1024, H=1024, NH=16, HD=64. fp32 I/O, bf16 MFMA internals.
// Pipeline: cvt3     : x,w_qkv,w_out fp32 -> bf16                  (~13 us)
//           gemm16<0>: qk = x@w_qkv^T cols<2048; V scatters to Vt  (51.5 GF)
//           attn     : no-max softmax flash attn, S^T trick        (34.4 GF)
//           gemm16<1>: out = O@w_out^T + b_out (fp32 out)          (17.2 GF)
// R10 (attn): cash in R9's LDS/VGPR savings as TLP. 64 q-rows/block ->
// grid (16,128) = 2048 blocks = 8 blocks/CU = 32 waves/CU (HW max; R9 was
// grid-limited to 4 blocks/CU). K/V staging doubles but is L2-resident
// (~11 TB/s needed vs 34.5 ceiling). P stays in registers via the kv-permuted
// K staging (R9): S^T C-layout regs packed = PV A-frags directly.

typedef short s16x8 __attribute__((ext_vector_type(8)));
typedef float f32x4 __attribute__((ext_vector_type(4)));
typedef unsigned int u32x2 __attribute__((ext_vector_type(2)));
typedef unsigned int u32x4 __attribute__((ext_vector_type(4)));

__device__ __forceinline__ unsigned short f2bf(float f) {   // RNE
    union { float f; unsigned u; } c; c.f = f;
    return (unsigned short)((c.u + 0x7FFFu + ((c.u >> 16) & 1u)) >> 16);
}
// pack 2 floats -> 2 bf16 (round-half-up) in 3 VALU ops via v_perm
__device__ __forceinline__ unsigned pack2bf(float a, float b) {
    union { float f; unsigned u; } ca, cb; ca.f = a; cb.f = b;
    return __builtin_amdgcn_perm(cb.u + 0x8000u, ca.u + 0x8000u, 0x07060302u);
}

#define GLOAD_LDS(g, l) __builtin_amdgcn_global_load_lds( \
    (const __attribute__((address_space(1))) void*)(g),   \
    (__attribute__((address_space(3))) void*)(l), 16, 0, 0)

// ---------------------------------------------------------------------------
// fp32 -> bf16 convert for the three input tensors.
// ---------------------------------------------------------------------------
__global__ __launch_bounds__(256) void cvt3(
    const float* __restrict__ s0, unsigned short* __restrict__ d0, int n0,
    const float* __restrict__ s1, unsigned short* __restrict__ d1, int n1,
    const float* __restrict__ s2, unsigned short* __restrict__ d2, int n2)
{
    long i = ((long)blockIdx.x * 256 + threadIdx.x) * 8;
    const float* s; unsigned short* d; long off;
    if (i < n0)                  { s = s0; d = d0; off = i; }
    else if (i < (long)n0 + n1)  { s = s1; d = d1; off = i - n0; }
    else                         { s = s2; d = d2; off = i - n0 - n1; }
    f32x4 a = *(const f32x4*)(s + off);
    f32x4 b = *(const f32x4*)(s + off + 4);
    u32x4 r;
    r[0] = pack2bf(a[0], a[1]); r[1] = pack2bf(a[2], a[3]);
    r[2] = pack2bf(b[0], b[1]); r[3] = pack2bf(b[2], b[3]);
    *(u32x4*)(d + off) = r;
}

// ---------------------------------------------------------------------------
// GEMM: C[M,N] = A[M,K]*B[N,K]^T, bf16 in, fp32 accum. 128x128 tile, BK=64,
// global_load_lds dwordx4. LDS [128][64] elems, XOR swizzle: logical 16B
// chunk q of row r at physical chunk q ^ (r&7) -> 2-way on banks (free).
// EPI=0: cols<1024 (Q) -> Cq bf16 scaled by 0.125*log2(e) (softmax prefold);
//        cols 1024..2047 (K) -> Cq bf16 unscaled; cols>=2048 (V) packed-
//        scatter to Cv = Vt[(b*16+h)*64+d][l] bf16.
// EPI=1: Cf fp32 + bias.
// ---------------------------------------------------------------------------
template<int EPI>
__global__ __launch_bounds__(256) void gemm16(
    const unsigned short* __restrict__ A, const unsigned short* __restrict__ Bm,
    unsigned short* __restrict__ Cq, unsigned short* __restrict__ Cv,
    float* __restrict__ Cf, const float* __restrict__ bias,
    int N, int K)
{
    __shared__ unsigned short As[128 * 64];
    __shared__ unsigned short Bs[128 * 64];
    const int tid = threadIdx.x, lane = tid & 63, wave = tid >> 6;
    const int quad = lane >> 4, l16 = lane & 15;
    const int wm = (wave >> 1) * 64, wn = (wave & 1) * 64;
    const int m0 = blockIdx.y * 128, n0 = blockIdx.x * 128;

    const int prow = tid >> 3;
    const int qch  = (tid & 7) ^ (prow & 7);
    const unsigned short* gA[4];
    const unsigned short* gB[4];
    #pragma unroll
    for (int c = 0; c < 4; ++c) {
        gA[c] = A + (size_t)(m0 + c * 32 + prow) * K + qch * 8;
        gB[c] = Bm + (size_t)(n0 + c * 32 + prow) * K + qch * 8;
    }
    const int sw = l16 & 7;   // frag-read swizzle

    f32x4 acc[4][4] = {};
    for (int k0 = 0; k0 < K; k0 += 64) {
        __syncthreads();
        #pragma unroll
        for (int c = 0; c < 4; ++c) {
            GLOAD_LDS(gA[c], As + (c * 256 + tid) * 8);
            GLOAD_LDS(gB[c], Bs + (c * 256 + tid) * 8);
            gA[c] += 64; gB[c] += 64;
        }
        __syncthreads();
        #pragma unroll
        for (int s = 0; s < 2; ++s) {
            s16x8 af[4], bf[4];
            const int pc = ((s * 4 + quad) ^ sw) * 8;
            #pragma unroll
            for (int i = 0; i < 4; ++i)
                af[i] = *(const s16x8*)(As + (wm + i * 16 + l16) * 64 + pc);
            #pragma unroll
            for (int j = 0; j < 4; ++j)
                bf[j] = *(const s16x8*)(Bs + (wn + j * 16 + l16) * 64 + pc);
            #pragma unroll
            for (int i = 0; i < 4; ++i)
                #pragma unroll
                for (int j = 0; j < 4; ++j)
                    acc[i][j] = __builtin_amdgcn_mfma_f32_16x16x32_bf16(af[i], bf[j], acc[i][j], 0, 0, 0);
        }
    }

    // epilogue: C/D layout col=lane&15, row=quad*4+reg
    if (EPI == 1) {
        #pragma unroll
        for (int j = 0; j < 4; ++j) {
            int col = n0 + wn + j * 16 + l16;
            float bv = bias[col];
            #pragma unroll
            for (int i = 0; i < 4; ++i)
                #pragma unroll
                for (int r = 0; r < 4; ++r)
                    Cf[(size_t)(m0 + wm + i * 16 + quad * 4 + r) * N + col] = acc[i][j][r] + bv;
        }
    } else if (n0 < 2048) {
        // Q region: prefold softmax scale (1/8) and log2(e) for native exp2
        const float qs = (n0 < 1024) ? 0.18033688f : 1.0f;   // 0.125*log2(e)
        #pragma unroll
        for (int j = 0; j < 4; ++j) {
            int col = n0 + wn + j * 16 + l16;
            #pragma unroll
            for (int i = 0; i < 4; ++i)
                #pragma unroll
                for (int r = 0; r < 4; ++r)
                    Cq[(size_t)(m0 + wm + i * 16 + quad * 4 + r) * 2048 + col] = f2bf(acc[i][j][r] * qs);
        }
    } else {
        // V region: lane's r=0..3 are 4 consecutive l -> one 8B packed store
        #pragma unroll
        for (int j = 0; j < 4; ++j) {
            int dcol = n0 + wn + j * 16 + l16 - 2048;
            int hh = dcol >> 6, dd = dcol & 63;
            #pragma unroll
            for (int i = 0; i < 4; ++i) {
                int row = m0 + wm + i * 16 + quad * 4;
                int bb = row >> 10, l = row & 1023;
                u32x2 pw;
                pw[0] = pack2bf(acc[i][j][0], acc[i][j][1]);
                pw[1] = pack2bf(acc[i][j][2], acc[i][j][3]);
                *(u32x2*)(Cv + (size_t)((bb * 16 + hh) * 64 + dd) * 1024 + l) = pw;
            }
        }
    }
}

// ---------------------------------------------------------------------------
// Flash attention, no-max softmax (Q pre-scaled by 0.125*log2e -> bare exp2),
// S^T trick with kv-permuted K staging so P's packed C-layout registers are
// directly the PV A-fragments (no P LDS round-trip).
// K staging permutation: LDS row rho = 16t+4u+r holds kv = 32(t>>1)+8u+4(t&1)+r.
// 64 q-rows/block, grid (16 qtile, 128 bh) = 2048 blocks = 8 blocks/CU
// = 32 waves/CU (HW max). LDS 16.4 KB.
// ---------------------------------------------------------------------------
__global__ __launch_bounds__(256) void attn(
    const unsigned short* __restrict__ qk, const unsigned short* __restrict__ Vt,
    unsigned short* __restrict__ O)
{
    __shared__ unsigned short Ks[64 * 64];   // [rho][d] kv-permuted, swizzled
    __shared__ unsigned short Vs[64 * 64];   // [d][kv]  natural, swizzled

    const int bh = blockIdx.y, b = bh >> 4, hh = bh & 15;
    const int q0 = blockIdx.x * 64;
    const int tid = threadIdx.x, lane = tid & 63, wave = tid >> 6;
    const int quad = lane >> 4, l16 = lane & 15;

    // Q frags direct from global: B-operand, n=q=wave*16+l16, k=s*32+quad*8
    const unsigned short* qrow =
        qk + (size_t)(b * 1024 + q0 + wave * 16 + l16) * 2048 + hh * 64;
    s16x8 qf[2];
    qf[0] = *(const s16x8*)(qrow + quad * 8);
    qf[1] = *(const s16x8*)(qrow + 32 + quad * 8);

    // Staging: wave covers LDS rows rho0 = wave*16+rl and rho1 = rho0+8
    // (rl = lane>>3); chunk swizzle qc = (lane&7) ^ (rho&7), rho&7 == rl.
    // K source rows are the PERMUTED kv for each rho (t = wave for both).
    const int rl = lane >> 3;
    const int qc = (lane & 7) ^ rl;
    const int u0 = rl >> 2, r0 = rl & 3;
    const int kvbase = 32 * (wave >> 1) + 4 * (wave & 1) + r0;
    const int kv0 = kvbase + 8 * u0;          // for LDS row wave*16 + rl
    const int kv1 = kvbase + 8 * (2 + u0);    // for LDS row wave*16 + 8 + rl
    const unsigned short* srcK0 = qk + (size_t)(b * 1024 + kv0) * 2048 + 1024 + hh * 64 + qc * 8;
    const unsigned short* srcK1 = qk + (size_t)(b * 1024 + kv1) * 2048 + 1024 + hh * 64 + qc * 8;
    const unsigned short* srcV0 = Vt + (size_t)(bh * 64 + wave * 16 + rl) * 1024 + qc * 8;
    const unsigned short* srcV1 = Vt + (size_t)(bh * 64 + wave * 16 + 8 + rl) * 1024 + qc * 8;
    unsigned short* dK0 = Ks + (wave * 16 + rl) * 64 + (lane & 7) * 8;
    unsigned short* dK1 = Ks + (wave * 16 + 8 + rl) * 64 + (lane & 7) * 8;
    unsigned short* dV0 = Vs + (wave * 16 + rl) * 64 + (lane & 7) * 8;
    unsigned short* dV1 = Vs + (wave * 16 + 8 + rl) * 64 + (lane & 7) * 8;

    const int sw = l16 & 7;   // frag-read swizzle

    f32x4 Oacc[4] = {};
    float lsum = 0.0f;

    for (int kv = 0; kv < 1024; kv += 64) {
        __syncthreads();
        GLOAD_LDS(srcK0, dK0);
        GLOAD_LDS(srcK1, dK1);
        GLOAD_LDS(srcV0, dV0);
        GLOAD_LDS(srcV1, dV1);
        srcK0 += (size_t)64 * 2048; srcK1 += (size_t)64 * 2048;
        srcV0 += 64; srcV1 += 64;
        __syncthreads();   // vmcnt(0) drain -> K,V in LDS

        // S^T = K Q^T : tile t rows = permuted kv, col q = l16
        f32x4 Sacc[4] = {};
        #pragma unroll
        for (int t = 0; t < 4; ++t) {
            #pragma unroll
            for (int s = 0; s < 2; ++s) {
                s16x8 kf = *(const s16x8*)(Ks + (t * 16 + l16) * 64 + ((s * 4 + quad) ^ sw) * 8);
                Sacc[t] = __builtin_amdgcn_mfma_f32_16x16x32_bf16(kf, qf[s], Sacc[t], 0, 0, 0);
            }
        }
        // p = 2^s; per-lane row-sum; pack pairs (these ARE the PV A-frags)
        unsigned upw[4][2];
        #pragma unroll
        for (int t = 0; t < 4; ++t) {
            float p0 = __builtin_amdgcn_exp2f(Sacc[t][0]);
            float p1 = __builtin_amdgcn_exp2f(Sacc[t][1]);
            float p2 = __builtin_amdgcn_exp2f(Sacc[t][2]);
            float p3 = __builtin_amdgcn_exp2f(Sacc[t][3]);
            lsum += (p0 + p1) + (p2 + p3);
            upw[t][0] = pack2bf(p0, p1);
            upw[t][1] = pack2bf(p2, p3);
        }
        // O += P V^T : A = packed P (register), B = Vs[n=d] (natural)
        #pragma unroll
        for (int s = 0; s < 2; ++s) {
            u32x4 aw;
            aw[0] = upw[2 * s][0];     aw[1] = upw[2 * s][1];
            aw[2] = upw[2 * s + 1][0]; aw[3] = upw[2 * s + 1][1];
            s16x8 pf;
            __builtin_memcpy(&pf, &aw, 16);
            #pragma unroll
            for (int jd = 0; jd < 4; ++jd) {
                s16x8 vf = *(const s16x8*)(Vs + (jd * 16 + l16) * 64 + ((s * 4 + quad) ^ sw) * 8);
                Oacc[jd] = __builtin_amdgcn_mfma_f32_16x16x32_bf16(pf, vf, Oacc[jd], 0, 0, 0);
            }
        }
    }

    // row-sum reduce + write (sum over quads is permutation-invariant)
    lsum += __shfl_xor(lsum, 16, 64);
    lsum += __shfl_xor(lsum, 32, 64);
    float rinv[4];
    #pragma unroll
    for (int r = 0; r < 4; ++r)
        rinv[r] = 1.0f / __shfl(lsum, quad * 4 + r, 64);
    #pragma unroll
    for (int j = 0; j < 4; ++j)
        #pragma unroll
        for (int r = 0; r < 4; ++r) {
            int row = q0 + wave * 16 + quad * 4 + r;
            int col = hh * 64 + j * 16 + l16;
            O[(size_t)(b * 1024 + row) * 1024 + col] = f2bf(Oacc[j][r] * rinv[r]);
        }
}

extern "C" void kernel_launch(void* const* d_in, const int* in_sizes, int n_in,
                              void* d_out, int out_size, void* d_ws, size_t ws_size,
                              hipStream_t stream) {
    const float* x     = (const float*)d_in[0];   // [8192,1024]
    const float* w_qkv = (const float*)d_in[1];   // [3072,1024]
    const float* w_out = (const float*)d_in[2];   // [1024,1024]
    const float* b_out = (const float*)d_in[3];   // [1024]
    float* out = (float*)d_out;                   // [8192,1024] fp32

    const int nx = 8192 * 1024, nwq = 3072 * 1024, nwo = 1024 * 1024;
    unsigned short* xb  = (unsigned short*)d_ws;          // 16.8 MB (dead after gemm1)
    unsigned short* wqb = xb + nx;                        //  6.3 MB
    unsigned short* wob = wqb + nwq;                      //  2.1 MB
    unsigned short* qkb = wob + nwo;                      // [8192,2048] Q|K, 33.6 MB
    unsigned short* Vt  = qkb + (size_t)8192 * 2048;      // [128*64,1024], 16.8 MB
    unsigned short* Ob  = xb;                             // alias: xb dead after gemm1

    dim3 blk(256);
    cvt3<<<6144, blk, 0, stream>>>(x, xb, nx, w_qkv, wqb, nwq, w_out, wob, nwo);
    gemm16<0><<<dim3(24, 64), blk, 0, stream>>>(xb, wqb, qkb, Vt, nullptr, nullptr, 3072, 1024);
    attn<<<dim3(16, 128), blk, 0, stream>>>(qkb, Vt, Ob);
    gemm16<1><<<dim3(8, 64), blk, 0, stream>>>(Ob, wob, nullptr, nullptr, out, b_out, 1024, 1024);
}